// Round 5
// baseline (174.678 us; speedup 1.0000x reference)
//
#include <hip/hip_runtime.h>

typedef __attribute__((ext_vector_type(8))) short short8;
typedef __attribute__((ext_vector_type(16))) float f32x16;

#define B_    8
#define N_TOK 4096
#define C_    512
#define H_    16
#define K_TOK 1024
#define D_    64
#define BM    128
#define BK    64

// fp32 -> bf16, round-to-nearest-even
static __device__ inline ushort f2b(float f) {
  unsigned u = __builtin_bit_cast(unsigned, f);
  u += 0x7fff + ((u >> 16) & 1);
  return (ushort)(u >> 16);
}

// W fp32 [H][C][D] -> WT bf16 [H][D][C], LDS-tiled transpose (coalesced both sides)
__global__ __launch_bounds__(256) void wt_convert(const float* __restrict__ W,
                                                  ushort* __restrict__ WT) {
  __shared__ float tile[64][65];   // +1 pad: column reads conflict-free
  int h   = blockIdx.x >> 3;
  int kc0 = (blockIdx.x & 7) << 6;
  int t   = threadIdx.x;
  const float* Wh = W + ((size_t)h * C_ + kc0) * D_;
#pragma unroll
  for (int p = 0; p < 4; ++p) {
    int k  = p * 16 + (t >> 4);
    int n4 = (t & 15) * 4;
    float4 v = *reinterpret_cast<const float4*>(&Wh[k * D_ + n4]);  // coalesced
    tile[k][n4 + 0] = v.x; tile[k][n4 + 1] = v.y;
    tile[k][n4 + 2] = v.z; tile[k][n4 + 3] = v.w;
  }
  __syncthreads();
  ushort* WTh = WT + (size_t)h * D_ * C_;
#pragma unroll
  for (int p = 0; p < 4; ++p) {
    int n  = p * 16 + (t >> 4);
    int k4 = (t & 15) * 4;
    ushort4 o;
    o.x = f2b(tile[k4 + 0][n]); o.y = f2b(tile[k4 + 1][n]);
    o.z = f2b(tile[k4 + 2][n]); o.w = f2b(tile[k4 + 3][n]);
    *reinterpret_cast<ushort4*>(&WTh[n * C_ + kc0 + k4]) = o;       // coalesced
  }
}

__global__ __launch_bounds__(256, 4) void gather_gemm(
    const float* __restrict__ X, const int* __restrict__ ind,
    const ushort* __restrict__ WT, float* __restrict__ out) {
  __shared__ ushort Asu[BM * BK];   // 16 KB, XOR-swizzled 16B chunks
  __shared__ ushort Bsu[D_ * BK];   // 8 KB
  __shared__ int inds[BM];

  int bid = blockIdx.x;
  // XCD swizzle: 1024 blocks, 8 XCDs -> XCD x gets batch x (X[b] slice L2-local)
  int nb = (bid & 7) * 128 + (bid >> 3);
  int b  = nb >> 7;
  int h  = (nb >> 3) & 15;
  int mt = nb & 7;

  int tid = threadIdx.x;
  if (tid < BM) inds[tid] = ind[(size_t)(b * H_ + h) * K_TOK + mt * BM + tid];
  __syncthreads();

  int lane = tid & 63;
  int wave = tid >> 6;
  int r16  = tid >> 4;   // 0..15 staging row group
  int c4   = tid & 15;   // 0..15 staging col group (4 floats)

  f32x16 acc0 = {};
  f32x16 acc1 = {};

  const float*  Xb  = X + (size_t)b * N_TOK * C_;
  const ushort* wth = WT + (size_t)(h * D_) * C_;

  int arow = (wave << 5) + (lane & 31);
  int hi   = lane >> 5;

  // hoisted 32-bit gather offsets (idx*512 + c4*4 < 2^21)
  int aoff[8];
#pragma unroll
  for (int rr = 0; rr < 8; ++rr)
    aoff[rr] = inds[rr * 16 + r16] * C_ + c4 * 4;
  int boff[2];
#pragma unroll
  for (int t2 = 0; t2 < 2; ++t2) {
    int lin = tid + 256 * t2;
    boff[t2] = (lin >> 3) * C_ + (lin & 7) * 8;
  }

  // prologue: loads for kc=0
  float4 av[8]; uint4 bv[2];
#pragma unroll
  for (int rr = 0; rr < 8; ++rr)
    av[rr] = *reinterpret_cast<const float4*>(&Xb[aoff[rr]]);
#pragma unroll
  for (int t2 = 0; t2 < 2; ++t2)
    bv[t2] = *reinterpret_cast<const uint4*>(&wth[boff[t2]]);

#pragma unroll
  for (int kc = 0; kc < C_ / BK; ++kc) {
    if (kc) __syncthreads();

    // stage current tile to LDS (cvt fp32->bf16 on the way)
#pragma unroll
    for (int rr = 0; rr < 8; ++rr) {
      int row = rr * 16 + r16;
      ushort4 w;
      w.x = f2b(av[rr].x); w.y = f2b(av[rr].y);
      w.z = f2b(av[rr].z); w.w = f2b(av[rr].w);
      int sw = (c4 >> 1) ^ (row & 7);
      *reinterpret_cast<ushort4*>(&Asu[row * 64 + sw * 8 + (c4 & 1) * 4]) = w;
    }
#pragma unroll
    for (int t2 = 0; t2 < 2; ++t2) {
      int lin = tid + 256 * t2;
      int n  = lin >> 3;
      int cc = lin & 7;
      *reinterpret_cast<uint4*>(&Bsu[n * 64 + ((cc ^ (n & 7)) << 3)]) = bv[t2];
    }

    // prefetch next tile into registers — in flight across barrier + MFMA
    float4 av2[8]; uint4 bv2[2];
    if (kc < C_ / BK - 1) {
#pragma unroll
      for (int rr = 0; rr < 8; ++rr)
        av2[rr] = *reinterpret_cast<const float4*>(&Xb[aoff[rr] + (kc + 1) * BK]);
#pragma unroll
      for (int t2 = 0; t2 < 2; ++t2)
        bv2[t2] = *reinterpret_cast<const uint4*>(&wth[boff[t2] + (kc + 1) * BK]);
    }
    __syncthreads();

    // compute: 4 x (2 mfma 32x32x16) over this 64-wide K chunk
#pragma unroll
    for (int kk = 0; kk < 4; ++kk) {
      int ka = kk * 2 + hi;
      short8 af = *reinterpret_cast<short8*>(
          &Asu[arow * 64 + ((ka ^ (arow & 7)) << 3)]);
      int n0  = lane & 31;
      int swb = (ka ^ (n0 & 7)) << 3;
      short8 bf0 = *reinterpret_cast<short8*>(&Bsu[n0 * 64 + swb]);
      short8 bf1 = *reinterpret_cast<short8*>(&Bsu[(n0 + 32) * 64 + swb]);
      acc0 = __builtin_amdgcn_mfma_f32_32x32x16_bf16(af, bf0, acc0, 0, 0, 0);
      acc1 = __builtin_amdgcn_mfma_f32_32x32x16_bf16(af, bf1, acc1, 0, 0, 0);
    }

    if (kc < C_ / BK - 1) {
#pragma unroll
      for (int rr = 0; rr < 8; ++rr) av[rr] = av2[rr];
      bv[0] = bv2[0]; bv[1] = bv2[1];
    }
  }

  // epilogue: C/D layout col=lane&31, row=(reg&3)+8*(reg>>2)+4*(lane>>5)
  size_t obase = ((size_t)(b * H_ + h) * K_TOK + mt * BM + (wave << 5)) * D_;
  int col = lane & 31;
#pragma unroll
  for (int reg = 0; reg < 16; ++reg) {
    int r = (reg & 3) + 8 * (reg >> 2) + 4 * hi;
    out[obase + (size_t)r * D_ + col]      = acc0[reg];
    out[obase + (size_t)r * D_ + 32 + col] = acc1[reg];
  }
}

extern "C" void kernel_launch(void* const* d_in, const int* in_sizes, int n_in,
                              void* d_out, int out_size, void* d_ws, size_t ws_size,
                              hipStream_t stream) {
  const float* X  = (const float*)d_in[0];
  const int*  ind = (const int*)d_in[1];
  const float* W  = (const float*)d_in[2];
  float* out = (float*)d_out;
  ushort* WT = (ushort*)d_ws;  // 1 MB bf16 [H][D][C]

  wt_convert<<<dim3(128), dim3(256), 0, stream>>>(W, WT);
  gather_gemm<<<dim3(1024), dim3(256), 0, stream>>>(X, ind, WT, out);
}

// Round 6
// 158.698 us; speedup vs baseline: 1.1007x; 1.1007x over previous
//
#include <hip/hip_runtime.h>

typedef __attribute__((ext_vector_type(8))) short short8;
typedef __attribute__((ext_vector_type(16))) float f32x16;

#define B_    8
#define N_TOK 4096
#define C_    512
#define H_    16
#define K_TOK 1024
#define D_    64
#define BM    128
#define BK    64

// fp32 -> bf16, round-to-nearest-even
static __device__ inline ushort f2b(float f) {
  unsigned u = __builtin_bit_cast(unsigned, f);
  u += 0x7fff + ((u >> 16) & 1);
  return (ushort)(u >> 16);
}

// W fp32 [H][C][D] -> WT bf16 [H][D][C], LDS-tiled transpose (coalesced both sides)
__global__ __launch_bounds__(256) void wt_convert(const float* __restrict__ W,
                                                  ushort* __restrict__ WT) {
  __shared__ float tile[64][65];   // +1 pad: column reads conflict-free
  int h   = blockIdx.x >> 3;
  int kc0 = (blockIdx.x & 7) << 6;
  int t   = threadIdx.x;
  const float* Wh = W + ((size_t)h * C_ + kc0) * D_;
#pragma unroll
  for (int p = 0; p < 4; ++p) {
    int k  = p * 16 + (t >> 4);
    int n4 = (t & 15) * 4;
    float4 v = *reinterpret_cast<const float4*>(&Wh[k * D_ + n4]);  // coalesced
    tile[k][n4 + 0] = v.x; tile[k][n4 + 1] = v.y;
    tile[k][n4 + 2] = v.z; tile[k][n4 + 3] = v.w;
  }
  __syncthreads();
  ushort* WTh = WT + (size_t)h * D_ * C_;
#pragma unroll
  for (int p = 0; p < 4; ++p) {
    int n  = p * 16 + (t >> 4);
    int k4 = (t & 15) * 4;
    ushort4 o;
    o.x = f2b(tile[k4 + 0][n]); o.y = f2b(tile[k4 + 1][n]);
    o.z = f2b(tile[k4 + 2][n]); o.w = f2b(tile[k4 + 3][n]);
    *reinterpret_cast<ushort4*>(&WTh[n * C_ + kc0 + k4]) = o;       // coalesced
  }
}

// NOTE: no min-waves clamp — R5 showed __launch_bounds__(256,4) forced 64 VGPRs
// and spilled the prefetch registers to scratch (+134 MB scratch writes).
__global__ __launch_bounds__(256) void gather_gemm(
    const float* __restrict__ X, const int* __restrict__ ind,
    const ushort* __restrict__ WT, float* __restrict__ out) {
  __shared__ ushort Asu[BM * BK];   // 16 KB, XOR-swizzled 16B chunks
  __shared__ ushort Bsu[D_ * BK];   // 8 KB
  __shared__ int inds[BM];

  int bid = blockIdx.x;
  // XCD swizzle: 1024 blocks, 8 XCDs -> XCD x gets batch x (X[b] slice L2-local)
  int nb = (bid & 7) * 128 + (bid >> 3);
  int b  = nb >> 7;
  int h  = (nb >> 3) & 15;
  int mt = nb & 7;

  int tid = threadIdx.x;
  if (tid < BM) inds[tid] = ind[(size_t)(b * H_ + h) * K_TOK + mt * BM + tid];
  __syncthreads();

  int lane = tid & 63;
  int wave = tid >> 6;
  int r16  = tid >> 4;   // 0..15 staging row group
  int c4   = tid & 15;   // 0..15 staging col group (4 floats)

  f32x16 acc0 = {};
  f32x16 acc1 = {};

  const float*  Xb  = X + (size_t)b * N_TOK * C_;
  const ushort* wth = WT + (size_t)(h * D_) * C_;

  int arow = (wave << 5) + (lane & 31);
  int hi   = lane >> 5;

  // hoisted 32-bit gather offsets (idx*512 + c4*4 < 2^21)
  int aoff[8];
#pragma unroll
  for (int rr = 0; rr < 8; ++rr)
    aoff[rr] = inds[rr * 16 + r16] * C_ + c4 * 4;
  int boff[2];
#pragma unroll
  for (int t2 = 0; t2 < 2; ++t2) {
    int lin = tid + 256 * t2;
    boff[t2] = (lin >> 3) * C_ + (lin & 7) * 8;
  }

  // prologue: loads for kc=0
  float4 av[8]; uint4 bv[2];
#pragma unroll
  for (int rr = 0; rr < 8; ++rr)
    av[rr] = *reinterpret_cast<const float4*>(&Xb[aoff[rr]]);
#pragma unroll
  for (int t2 = 0; t2 < 2; ++t2)
    bv[t2] = *reinterpret_cast<const uint4*>(&wth[boff[t2]]);

#pragma unroll
  for (int kc = 0; kc < C_ / BK; ++kc) {
    if (kc) __syncthreads();

    // stage current tile to LDS (cvt fp32->bf16 on the way)
#pragma unroll
    for (int rr = 0; rr < 8; ++rr) {
      int row = rr * 16 + r16;
      ushort4 w;
      w.x = f2b(av[rr].x); w.y = f2b(av[rr].y);
      w.z = f2b(av[rr].z); w.w = f2b(av[rr].w);
      int sw = (c4 >> 1) ^ (row & 7);
      *reinterpret_cast<ushort4*>(&Asu[row * 64 + sw * 8 + (c4 & 1) * 4]) = w;
    }
#pragma unroll
    for (int t2 = 0; t2 < 2; ++t2) {
      int lin = tid + 256 * t2;
      int n  = lin >> 3;
      int cc = lin & 7;
      *reinterpret_cast<uint4*>(&Bsu[n * 64 + ((cc ^ (n & 7)) << 3)]) = bv[t2];
    }

    // prefetch next tile into registers — in flight across barrier + MFMA
    float4 av2[8]; uint4 bv2[2];
    if (kc < C_ / BK - 1) {
#pragma unroll
      for (int rr = 0; rr < 8; ++rr)
        av2[rr] = *reinterpret_cast<const float4*>(&Xb[aoff[rr] + (kc + 1) * BK]);
#pragma unroll
      for (int t2 = 0; t2 < 2; ++t2)
        bv2[t2] = *reinterpret_cast<const uint4*>(&wth[boff[t2] + (kc + 1) * BK]);
    }
    __syncthreads();

    // compute: 4 x (2 mfma 32x32x16) over this 64-wide K chunk
#pragma unroll
    for (int kk = 0; kk < 4; ++kk) {
      int ka = kk * 2 + hi;
      short8 af = *reinterpret_cast<short8*>(
          &Asu[arow * 64 + ((ka ^ (arow & 7)) << 3)]);
      int n0  = lane & 31;
      int swb = (ka ^ (n0 & 7)) << 3;
      short8 bf0 = *reinterpret_cast<short8*>(&Bsu[n0 * 64 + swb]);
      short8 bf1 = *reinterpret_cast<short8*>(&Bsu[(n0 + 32) * 64 + swb]);
      acc0 = __builtin_amdgcn_mfma_f32_32x32x16_bf16(af, bf0, acc0, 0, 0, 0);
      acc1 = __builtin_amdgcn_mfma_f32_32x32x16_bf16(af, bf1, acc1, 0, 0, 0);
    }

    if (kc < C_ / BK - 1) {
#pragma unroll
      for (int rr = 0; rr < 8; ++rr) av[rr] = av2[rr];
      bv[0] = bv2[0]; bv[1] = bv2[1];
    }
  }

  // epilogue: C/D layout col=lane&31, row=(reg&3)+8*(reg>>2)+4*(lane>>5)
  size_t obase = ((size_t)(b * H_ + h) * K_TOK + mt * BM + (wave << 5)) * D_;
  int col = lane & 31;
#pragma unroll
  for (int reg = 0; reg < 16; ++reg) {
    int r = (reg & 3) + 8 * (reg >> 2) + 4 * hi;
    out[obase + (size_t)r * D_ + col]      = acc0[reg];
    out[obase + (size_t)r * D_ + 32 + col] = acc1[reg];
  }
}

extern "C" void kernel_launch(void* const* d_in, const int* in_sizes, int n_in,
                              void* d_out, int out_size, void* d_ws, size_t ws_size,
                              hipStream_t stream) {
  const float* X  = (const float*)d_in[0];
  const int*  ind = (const int*)d_in[1];
  const float* W  = (const float*)d_in[2];
  float* out = (float*)d_out;
  ushort* WT = (ushort*)d_ws;  // 1 MB bf16 [H][D][C]

  wt_convert<<<dim3(128), dim3(256), 0, stream>>>(W, WT);
  gather_gemm<<<dim3(1024), dim3(256), 0, stream>>>(X, ind, WT, out);
}

// Round 8
// 128.034 us; speedup vs baseline: 1.3643x; 1.2395x over previous
//
#include <hip/hip_runtime.h>

typedef __attribute__((ext_vector_type(8))) short short8;
typedef __attribute__((ext_vector_type(16))) float f32x16;

#define B_    8
#define N_TOK 4096
#define C_    512
#define H_    16
#define K_TOK 1024
#define D_    64
#define BM    64
#define BK    64

// fp32 -> bf16, round-to-nearest-even
static __device__ inline ushort f2b(float f) {
  unsigned u = __builtin_bit_cast(unsigned, f);
  u += 0x7fff + ((u >> 16) & 1);
  return (ushort)(u >> 16);
}

// W fp32 [H][C][D] -> WT bf16 [H][D][C], LDS-tiled transpose (coalesced both sides)
__global__ __launch_bounds__(256) void wt_convert(const float* __restrict__ W,
                                                  ushort* __restrict__ WT) {
  __shared__ float tile[64][65];
  int h   = blockIdx.x >> 3;
  int kc0 = (blockIdx.x & 7) << 6;
  int t   = threadIdx.x;
  const float* Wh = W + ((size_t)h * C_ + kc0) * D_;
#pragma unroll
  for (int p = 0; p < 4; ++p) {
    int k  = p * 16 + (t >> 4);
    int n4 = (t & 15) * 4;
    float4 v = *reinterpret_cast<const float4*>(&Wh[k * D_ + n4]);
    tile[k][n4 + 0] = v.x; tile[k][n4 + 1] = v.y;
    tile[k][n4 + 2] = v.z; tile[k][n4 + 3] = v.w;
  }
  __syncthreads();
  ushort* WTh = WT + (size_t)h * D_ * C_;
#pragma unroll
  for (int p = 0; p < 4; ++p) {
    int n  = p * 16 + (t >> 4);
    int k4 = (t & 15) * 4;
    ushort4 o;
    o.x = f2b(tile[k4 + 0][n]); o.y = f2b(tile[k4 + 1][n]);
    o.z = f2b(tile[k4 + 2][n]); o.w = f2b(tile[k4 + 3][n]);
    *reinterpret_cast<ushort4*>(&WTh[n * C_ + kc0 + k4]) = o;
  }
}

// R2 dataflow (no reg-prefetch: hipcc spills it — R5/R6 evidence), BM=64 for
// 8 blocks/CU of independent barrier domains (TLP latency hiding).
__global__ __launch_bounds__(256) void gather_gemm(
    const float* __restrict__ X, const int* __restrict__ ind,
    const ushort* __restrict__ WT, float* __restrict__ out) {
  __shared__ ushort Asu[BM * BK];   // 8 KB, XOR-swizzled 16B chunks
  __shared__ ushort Bsu[D_ * BK];   // 8 KB
  __shared__ int inds[BM];

  int bid = blockIdx.x;
  // XCD swizzle: 2048 blocks, 8 XCDs -> XCD x gets batch x (X[b] slice L2-local)
  int nb = (bid & 7) * 256 + (bid >> 3);
  int b  = nb >> 8;
  int h  = (nb >> 4) & 15;
  int mt = nb & 15;

  int tid = threadIdx.x;
  if (tid < BM) inds[tid] = ind[(size_t)(b * H_ + h) * K_TOK + mt * BM + tid];
  __syncthreads();

  int lane = tid & 63;
  int wave = tid >> 6;
  int r16  = tid >> 4;   // 0..15 staging row group
  int c4   = tid & 15;   // 0..15 staging col group (4 floats)

  f32x16 acc = {};

  const float*  Xb  = X + (size_t)b * N_TOK * C_;
  const ushort* wth = WT + (size_t)(h * D_) * C_;

  int rh = wave >> 1;              // row half (0/1) -> rows rh*32..rh*32+31
  int ch = wave & 1;               // col half (0/1) -> cols ch*32..ch*32+31
  int arow = rh * 32 + (lane & 31);
  int brow = ch * 32 + (lane & 31);
  int hi   = lane >> 5;

  // hoisted 32-bit gather offsets
  int aoff[4];
#pragma unroll
  for (int rr = 0; rr < 4; ++rr)
    aoff[rr] = inds[rr * 16 + r16] * C_ + c4 * 4;
  int boff[2];
#pragma unroll
  for (int t2 = 0; t2 < 2; ++t2) {
    int lin = tid + 256 * t2;
    boff[t2] = (lin >> 3) * C_ + (lin & 7) * 8;
  }

  for (int kc = 0; kc < C_ / BK; ++kc) {
    if (kc) __syncthreads();

    // gather 64 rows x 64 fp32 + B rows
    float4 av[4];
#pragma unroll
    for (int rr = 0; rr < 4; ++rr)
      av[rr] = *reinterpret_cast<const float4*>(&Xb[aoff[rr] + kc * BK]);
    uint4 bv[2];
#pragma unroll
    for (int t2 = 0; t2 < 2; ++t2)
      bv[t2] = *reinterpret_cast<const uint4*>(&wth[boff[t2] + kc * BK]);

    // stage to LDS (cvt fp32->bf16 on the way), XOR-swizzled
#pragma unroll
    for (int rr = 0; rr < 4; ++rr) {
      int row = rr * 16 + r16;
      ushort4 w;
      w.x = f2b(av[rr].x); w.y = f2b(av[rr].y);
      w.z = f2b(av[rr].z); w.w = f2b(av[rr].w);
      int sw = (c4 >> 1) ^ (row & 7);
      *reinterpret_cast<ushort4*>(&Asu[row * 64 + sw * 8 + (c4 & 1) * 4]) = w;
    }
#pragma unroll
    for (int t2 = 0; t2 < 2; ++t2) {
      int lin = tid + 256 * t2;
      int n  = lin >> 3;
      int cc = lin & 7;
      *reinterpret_cast<uint4*>(&Bsu[n * 64 + ((cc ^ (n & 7)) << 3)]) = bv[t2];
    }
    __syncthreads();

    // compute: 4 x mfma 32x32x16 per wave (wave owns 32x32 quadrant)
#pragma unroll
    for (int kk = 0; kk < 4; ++kk) {
      int ka = kk * 2 + hi;
      short8 af = *reinterpret_cast<short8*>(
          &Asu[arow * 64 + ((ka ^ (arow & 7)) << 3)]);
      short8 bf = *reinterpret_cast<short8*>(
          &Bsu[brow * 64 + ((ka ^ (brow & 7)) << 3)]);
      acc = __builtin_amdgcn_mfma_f32_32x32x16_bf16(af, bf, acc, 0, 0, 0);
    }
  }

  // epilogue: C/D layout col=lane&31, row=(reg&3)+8*(reg>>2)+4*(lane>>5)
  size_t obase = ((size_t)(b * H_ + h) * K_TOK + mt * BM + rh * 32) * D_;
  int col = ch * 32 + (lane & 31);
#pragma unroll
  for (int reg = 0; reg < 16; ++reg) {
    int r = (reg & 3) + 8 * (reg >> 2) + 4 * hi;
    out[obase + (size_t)r * D_ + col] = acc[reg];
  }
}

extern "C" void kernel_launch(void* const* d_in, const int* in_sizes, int n_in,
                              void* d_out, int out_size, void* d_ws, size_t ws_size,
                              hipStream_t stream) {
  const float* X  = (const float*)d_in[0];
  const int*  ind = (const int*)d_in[1];
  const float* W  = (const float*)d_in[2];
  float* out = (float*)d_out;
  ushort* WT = (ushort*)d_ws;  // 1 MB bf16 [H][D][C]

  wt_convert<<<dim3(128), dim3(256), 0, stream>>>(W, WT);
  gather_gemm<<<dim3(2048), dim3(256), 0, stream>>>(X, ind, WT, out);
}